// Round 14
// baseline (35.509 us; speedup 1.0000x reference)
//
#include <hip/hip_runtime.h>

#define NNODES 4096
#define INF_   256
#define HEADS  8
#define FDIM   64
#define HO     512            // HEADS*FDIM
#define NEDGES 131072
#define NEG_SLOPE 0.2f
#define MWORDS 128            // 4096 bits / 32 per row

#define ZB 512                // prep: zero-mask blocks
#define WTB 32                // prep: W-transpose tiles
#define GEMM_BLOCKS 512       // 64 row-tiles x 8 col-tiles(heads)
#define ADJ_BLOCKS  512       // 131072 / 256
#define LCAP 1092             // per-row neighbor list capacity (max deg here ~70)

typedef unsigned short ushort_t;
typedef short bf16x8 __attribute__((ext_vector_type(8)));
typedef float f32x4  __attribute__((ext_vector_type(4)));

union U16x8 { uint4 u; bf16x8 v; };

__device__ __forceinline__ float bf16_to_f32(ushort_t u) {
    union { unsigned int i; float f; } c;
    c.i = ((unsigned int)u) << 16;
    return c.f;
}
__device__ __forceinline__ ushort_t f32_to_bf16(float f) {
    union { float f; unsigned int i; } c;
    c.f = f;
    unsigned int r = c.i + 0x7FFF + ((c.i >> 16) & 1);  // RNE
    return (ushort_t)(r >> 16);
}
// packed f32x2 -> bf16x2, hardware RNE (R11 verified: absmax identical to manual RNE)
__device__ __forceinline__ unsigned int cvt_pk_bf16(float lo, float hi) {
    unsigned int r;
    asm("v_cvt_pk_bf16_f32 %0, %1, %2" : "=v"(r) : "v"(lo), "v"(hi));
    return r;
}

// ============ prep: zero mask || W -> W^T bf16 (LDS-tiled) ============
__global__ __launch_bounds__(256) void prep_kernel(const float* __restrict__ W,
                                                   unsigned int* __restrict__ mask,
                                                   ushort_t* __restrict__ wt) {
    __shared__ float tile[64][65];
    int b = blockIdx.x, t = threadIdx.x;
    if (b < ZB) {
        *reinterpret_cast<uint4*>(mask + (size_t)(b * 256 + t) * 4) = make_uint4(0u, 0u, 0u, 0u);
    } else {
        // ---- W^T tile: W[k0..k0+63][n0..n0+63] -> wt[n][k], coalesced both sides ----
        int wb = b - ZB;               // 0..31
        int k0 = (wb >> 3) * 64;       // 4 k-tiles
        int n0 = (wb & 7) * 64;        // 8 n-tiles
        int row = t >> 2;
        #pragma unroll
        for (int it = 0; it < 4; ++it) {
            int f4 = (t & 3) + it * 4;  // 0..15
            float4 v = *reinterpret_cast<const float4*>(&W[(size_t)(k0 + row) * HO + n0 + f4 * 4]);
            tile[row][f4 * 4 + 0] = v.x;
            tile[row][f4 * 4 + 1] = v.y;
            tile[row][f4 * 4 + 2] = v.z;
            tile[row][f4 * 4 + 3] = v.w;
        }
        __syncthreads();
        int n = t >> 2;
        #pragma unroll
        for (int it = 0; it < 4; ++it) {
            int ch = (t & 3) + it * 4;  // k-chunk of 4
            ushort4 o;
            o.x = f32_to_bf16(tile[ch * 4 + 0][n]);
            o.y = f32_to_bf16(tile[ch * 4 + 1][n]);
            o.z = f32_to_bf16(tile[ch * 4 + 2][n]);
            o.w = f32_to_bf16(tile[ch * 4 + 3][n]);
            *reinterpret_cast<ushort4*>(&wt[(size_t)(n0 + n) * INF_ + k0 + ch * 4]) = o;
        }
    }
}

// ============ MFMA GEMM h = x@W, A+B LDS-staged (+ es/ed epilogue) || adjacency ============
__global__ __launch_bounds__(256) void gemm_adj(const float* __restrict__ x,
                                                const ushort_t* __restrict__ wt,
                                                const float* __restrict__ a,
                                                const int* __restrict__ ei,
                                                unsigned int* __restrict__ mask,
                                                ushort_t* __restrict__ hout,
                                                float* __restrict__ es,
                                                float* __restrict__ ed) {
    __shared__ ushort_t wls[64][264];   // B-tile [n-within-head][k], +8 pad -> free 2-way on b128 reads
    __shared__ ushort_t As[64][264];    // A-tile [row-within-tile][k], same padding
    int b = blockIdx.x, t = threadIdx.x;

    if (b >= GEMM_BLOCKS) {
        int e = (b - GEMM_BLOCKS) * 256 + t;
        if (e < NEDGES) {
            int src = ei[e];
            int dst = ei[NEDGES + e];
            atomicOr(&mask[src * MWORDS + (dst >> 5)], 1u << (dst & 31));
        }
        if (e < NNODES) {  // self loop (adj + eye)
            atomicOr(&mask[e * MWORDS + (e >> 5)], 1u << (e & 31));
        }
        return;
    }

    int bi = b >> 3, bj = b & 7;
    int w  = t >> 6, l = t & 63;
    int lr = l & 15, lk = l >> 4;

    // ---- stage wt rows [bj*64 .. +63] x 256k (32 KB) into LDS, coalesced ----
    #pragma unroll
    for (int it = 0; it < 8; ++it) {
        int flat = it * 256 + t;         // 2048 chunks of 8 bf16
        int row = flat >> 5;             // 0..63
        int c8  = flat & 31;             // k-chunk of 8
        uint4 v = *reinterpret_cast<const uint4*>(wt + (size_t)(bj * 64 + row) * INF_ + c8 * 8);
        *reinterpret_cast<uint4*>(&wls[row][c8 * 8]) = v;
    }
    // ---- stage x rows [bi*64 .. +63] (f32 -> bf16) into LDS, coalesced ----
    {
        const float* xsrc = x + (size_t)(bi * 64) * INF_;
        #pragma unroll
        for (int it = 0; it < 16; ++it) {
            int flat4 = it * 256 + t;    // float4 index within tile, 0..4095
            int row = flat4 >> 6;        // 64 float4 per row
            int c4  = flat4 & 63;
            float4 v = *reinterpret_cast<const float4*>(xsrc + (size_t)row * INF_ + c4 * 4);
            uint2 o;
            o.x = cvt_pk_bf16(v.x, v.y);
            o.y = cvt_pk_bf16(v.z, v.w);
            *reinterpret_cast<uint2*>(&As[row][c4 * 4]) = o;
        }
    }
    __syncthreads();

    f32x4 acc[4];
    #pragma unroll
    for (int c = 0; c < 4; ++c) acc[c] = (f32x4){0.f, 0.f, 0.f, 0.f};

    #pragma unroll
    for (int k0 = 0; k0 < INF_; k0 += 32) {
        U16x8 af;
        af.u = *reinterpret_cast<const uint4*>(&As[w * 16 + lr][k0 + lk * 8]);
        #pragma unroll
        for (int c = 0; c < 4; ++c) {
            U16x8 bf_;
            bf_.u = *reinterpret_cast<const uint4*>(&wls[c * 16 + lr][k0 + lk * 8]);
            acc[c] = __builtin_amdgcn_mfma_f32_16x16x32_bf16(af.v, bf_.v, acc[c], 0, 0, 0);
        }
    }

    // C/D: col=lane&15, row=(lane>>4)*4+reg
    int growbase = bi * 64 + w * 16 + lk * 4;
    #pragma unroll
    for (int c = 0; c < 4; ++c) {
        int gcol = bj * 64 + c * 16 + lr;
        #pragma unroll
        for (int r = 0; r < 4; ++r)
            hout[(size_t)(growbase + r) * HO + gcol] = f32_to_bf16(acc[c][r]);
    }

    float ps[4] = {0.f, 0.f, 0.f, 0.f}, pd[4] = {0.f, 0.f, 0.f, 0.f};
    #pragma unroll
    for (int c = 0; c < 4; ++c) {
        int col64 = c * 16 + lr;
        float as_ = a[bj * 2 * FDIM + col64];
        float ad_ = a[bj * 2 * FDIM + FDIM + col64];
        #pragma unroll
        for (int r = 0; r < 4; ++r) {
            ps[r] += acc[c][r] * as_;
            pd[r] += acc[c][r] * ad_;
        }
    }
    #pragma unroll
    for (int r = 0; r < 4; ++r) {
        #pragma unroll
        for (int off = 1; off < 16; off <<= 1) {
            ps[r] += __shfl_xor(ps[r], off, 16);
            pd[r] += __shfl_xor(pd[r], off, 16);
        }
        if (lr == 0) {
            int grow = growbase + r;
            es[grow * HEADS + bj] = ps[r];
            ed[grow * HEADS + bj] = pd[r];
        }
    }
}

// ============ aggregation: ONE WAVE per destination row, 4 neighbors in flight (R8) ============
__device__ __forceinline__ void agg_one(float wgt, uint4 v, float* acc) {
    acc[0] += wgt * bf16_to_f32((ushort_t)(v.x & 0xFFFF));
    acc[1] += wgt * bf16_to_f32((ushort_t)(v.x >> 16));
    acc[2] += wgt * bf16_to_f32((ushort_t)(v.y & 0xFFFF));
    acc[3] += wgt * bf16_to_f32((ushort_t)(v.y >> 16));
    acc[4] += wgt * bf16_to_f32((ushort_t)(v.z & 0xFFFF));
    acc[5] += wgt * bf16_to_f32((ushort_t)(v.z >> 16));
    acc[6] += wgt * bf16_to_f32((ushort_t)(v.w & 0xFFFF));
    acc[7] += wgt * bf16_to_f32((ushort_t)(v.w >> 16));
}

__global__ __launch_bounds__(256) void gat_aggregate(const ushort_t* __restrict__ h,
                                                     const float* __restrict__ es,
                                                     const float* __restrict__ ed,
                                                     const unsigned int* __restrict__ mask,
                                                     float* __restrict__ out) {
    int w = threadIdx.x >> 6, lane = threadIdx.x & 63;
    int i = blockIdx.x * 4 + w;
    __shared__ unsigned short list_s[4][LCAP];
    unsigned short* mylist = list_s[w];

    const unsigned int* row = mask + (size_t)i * MWORDS;
    unsigned int b0 = row[lane], b1 = row[64 + lane];
    int c0 = __popc(b0), c1 = __popc(b1);
    int s0 = c0;
    #pragma unroll
    for (int off = 1; off < 64; off <<= 1) { int v = __shfl_up(s0, off); if (lane >= off) s0 += v; }
    int tot0 = __shfl(s0, 63);
    int s1 = c1;
    #pragma unroll
    for (int off = 1; off < 64; off <<= 1) { int v = __shfl_up(s1, off); if (lane >= off) s1 += v; }
    int deg = tot0 + __shfl(s1, 63);
    int p0 = s0 - c0;
    int p1 = tot0 + s1 - c1;
    int base0 = lane * 32, base1 = (64 + lane) * 32;
    while (b0) {
        int bit = __ffs(b0) - 1; b0 &= b0 - 1;
        if (p0 < LCAP) mylist[p0] = (unsigned short)(base0 + bit);
        ++p0;
    }
    while (b1) {
        int bit = __ffs(b1) - 1; b1 &= b1 - 1;
        if (p1 < LCAP) mylist[p1] = (unsigned short)(base1 + bit);
        ++p1;
    }
    __syncthreads();

    int hh = lane >> 3;
    int f0 = lane * 8;
    float es_h = es[i * HEADS + hh];
    float acc[8] = {0.f, 0.f, 0.f, 0.f, 0.f, 0.f, 0.f, 0.f};
    float den = 0.f;
    int jj = 0;
    for (; jj + 4 <= deg; jj += 4) {
        int ja = mylist[jj], jb = mylist[jj + 1], jc = mylist[jj + 2], jd = mylist[jj + 3];
        float ea = ed[ja * HEADS + hh];
        float eb = ed[jb * HEADS + hh];
        float ec = ed[jc * HEADS + hh];
        float ee = ed[jd * HEADS + hh];
        uint4 va = *reinterpret_cast<const uint4*>(h + (size_t)ja * HO + f0);
        uint4 vb = *reinterpret_cast<const uint4*>(h + (size_t)jb * HO + f0);
        uint4 vc = *reinterpret_cast<const uint4*>(h + (size_t)jc * HO + f0);
        uint4 vd = *reinterpret_cast<const uint4*>(h + (size_t)jd * HO + f0);
        float sa = es_h + ea; sa = sa > 0.f ? sa : NEG_SLOPE * sa;
        float sb = es_h + eb; sb = sb > 0.f ? sb : NEG_SLOPE * sb;
        float sc = es_h + ec; sc = sc > 0.f ? sc : NEG_SLOPE * sc;
        float sd = es_h + ee; sd = sd > 0.f ? sd : NEG_SLOPE * sd;
        float wa = __expf(sa), wb = __expf(sb), wc = __expf(sc), wd = __expf(sd);
        den += (wa + wb) + (wc + wd);
        agg_one(wa, va, acc);
        agg_one(wb, vb, acc);
        agg_one(wc, vc, acc);
        agg_one(wd, vd, acc);
    }
    for (; jj < deg; ++jj) {
        int ja = mylist[jj];
        float ea = ed[ja * HEADS + hh];
        uint4 va = *reinterpret_cast<const uint4*>(h + (size_t)ja * HO + f0);
        float sa = es_h + ea; sa = sa > 0.f ? sa : NEG_SLOPE * sa;
        float wa = __expf(sa);
        den += wa;
        agg_one(wa, va, acc);
    }

    float inv = 1.0f / den;
    f32x4 o0 = {acc[0] * inv, acc[1] * inv, acc[2] * inv, acc[3] * inv};
    f32x4 o1 = {acc[4] * inv, acc[5] * inv, acc[6] * inv, acc[7] * inv};
    float* op = out + (size_t)i * HO + f0;
    __builtin_nontemporal_store(o0, reinterpret_cast<f32x4*>(op));
    __builtin_nontemporal_store(o1, reinterpret_cast<f32x4*>(op + 4));
}

extern "C" void kernel_launch(void* const* d_in, const int* in_sizes, int n_in,
                              void* d_out, int out_size, void* d_ws, size_t ws_size,
                              hipStream_t stream) {
    const float* x  = (const float*)d_in[0];
    const int*   ei = (const int*)d_in[1];
    const float* W  = (const float*)d_in[2];
    const float* a  = (const float*)d_in[3];
    float* out = (float*)d_out;

    char* ws = (char*)d_ws;
    ushort_t* h  = (ushort_t*)ws;                               // 4 MB
    float* es = (float*)(ws + (size_t)NNODES * HO * 2);         // 128 KB
    float* ed = es + NNODES * HEADS;                            // 128 KB
    unsigned int* mask = (unsigned int*)(ed + NNODES * HEADS);  // 2 MB
    ushort_t* wt = (ushort_t*)(mask + (size_t)NNODES * MWORDS); // 256 KB

    hipLaunchKernelGGL(prep_kernel, dim3(ZB + WTB), dim3(256), 0, stream, W, mask, wt);
    hipLaunchKernelGGL(gemm_adj, dim3(GEMM_BLOCKS + ADJ_BLOCKS), dim3(256), 0, stream,
                       x, wt, a, ei, mask, h, es, ed);
    hipLaunchKernelGGL(gat_aggregate, dim3(NNODES / 4), dim3(256), 0, stream, h, es, ed, mask, out);
}

// Round 15
// 35.050 us; speedup vs baseline: 1.0131x; 1.0131x over previous
//
#include <hip/hip_runtime.h>

#define NNODES 4096
#define INF_   256
#define HEADS  8
#define FDIM   64
#define HO     512            // HEADS*FDIM
#define NEDGES 131072
#define NEG_SLOPE 0.2f
#define MWORDS 128            // 4096 bits / 32 per row

#define ZB 512                // prep: zero-mask blocks
#define XB 1024               // prep: x-convert blocks
#define WTB 32                // prep: W-transpose tiles
#define GEMM_BLOCKS 512       // 64 row-tiles x 8 col-tiles(heads)
#define ADJ_BLOCKS  512       // 131072 / 256
#define LCAP 1092             // per-row neighbor list capacity (max deg here ~70)

typedef unsigned short ushort_t;
typedef short bf16x8 __attribute__((ext_vector_type(8)));
typedef float f32x4  __attribute__((ext_vector_type(4)));

union U16x8 { uint4 u; bf16x8 v; };

__device__ __forceinline__ float bf16_to_f32(ushort_t u) {
    union { unsigned int i; float f; } c;
    c.i = ((unsigned int)u) << 16;
    return c.f;
}
__device__ __forceinline__ ushort_t f32_to_bf16(float f) {
    union { float f; unsigned int i; } c;
    c.f = f;
    unsigned int r = c.i + 0x7FFF + ((c.i >> 16) & 1);  // RNE
    return (ushort_t)(r >> 16);
}

// ============ prep: zero mask || x -> bf16 row-major || W -> W^T bf16 (LDS-tiled) ============
__global__ __launch_bounds__(256) void prep_kernel(const float* __restrict__ x,
                                                   const float* __restrict__ W,
                                                   unsigned int* __restrict__ mask,
                                                   ushort_t* __restrict__ xb,
                                                   ushort_t* __restrict__ wt) {
    __shared__ float tile[64][65];
    int b = blockIdx.x, t = threadIdx.x;
    if (b < ZB) {
        *reinterpret_cast<uint4*>(mask + (size_t)(b * 256 + t) * 4) = make_uint4(0u, 0u, 0u, 0u);
    } else if (b < ZB + XB) {
        int i = (b - ZB) * 256 + t;
        float4 v = *reinterpret_cast<const float4*>(x + (size_t)i * 4);
        ushort4 o;
        o.x = f32_to_bf16(v.x); o.y = f32_to_bf16(v.y);
        o.z = f32_to_bf16(v.z); o.w = f32_to_bf16(v.w);
        *reinterpret_cast<ushort4*>(xb + (size_t)i * 4) = o;
    } else {
        // ---- W^T tile: W[k0..k0+63][n0..n0+63] -> wt[n][k], coalesced both sides ----
        int wb = b - ZB - XB;          // 0..31
        int k0 = (wb >> 3) * 64;       // 4 k-tiles
        int n0 = (wb & 7) * 64;        // 8 n-tiles
        int row = t >> 2;
        #pragma unroll
        for (int it = 0; it < 4; ++it) {
            int f4 = (t & 3) + it * 4;  // 0..15
            float4 v = *reinterpret_cast<const float4*>(&W[(size_t)(k0 + row) * HO + n0 + f4 * 4]);
            tile[row][f4 * 4 + 0] = v.x;
            tile[row][f4 * 4 + 1] = v.y;
            tile[row][f4 * 4 + 2] = v.z;
            tile[row][f4 * 4 + 3] = v.w;
        }
        __syncthreads();
        int n = t >> 2;
        #pragma unroll
        for (int it = 0; it < 4; ++it) {
            int ch = (t & 3) + it * 4;  // k-chunk of 4
            ushort4 o;
            o.x = f32_to_bf16(tile[ch * 4 + 0][n]);
            o.y = f32_to_bf16(tile[ch * 4 + 1][n]);
            o.z = f32_to_bf16(tile[ch * 4 + 2][n]);
            o.w = f32_to_bf16(tile[ch * 4 + 3][n]);
            *reinterpret_cast<ushort4*>(&wt[(size_t)(n0 + n) * INF_ + k0 + ch * 4]) = o;
        }
    }
}

// ============ MFMA GEMM h = x@W, B-tile LDS-staged (+ es/ed epilogue) || adjacency ============
__global__ __launch_bounds__(256) void gemm_adj(const ushort_t* __restrict__ xb,
                                                const ushort_t* __restrict__ wt,
                                                const float* __restrict__ a,
                                                const int* __restrict__ ei,
                                                unsigned int* __restrict__ mask,
                                                ushort_t* __restrict__ hout,
                                                float* __restrict__ es,
                                                float* __restrict__ ed) {
    __shared__ ushort_t wls[64][264];   // B-tile [n-within-head][k], +8 pad -> free 2-way on b128 reads
    int b = blockIdx.x, t = threadIdx.x;

    if (b >= GEMM_BLOCKS) {
        int e = (b - GEMM_BLOCKS) * 256 + t;
        if (e < NEDGES) {
            int src = ei[e];
            int dst = ei[NEDGES + e];
            atomicOr(&mask[src * MWORDS + (dst >> 5)], 1u << (dst & 31));
        }
        if (e < NNODES) {  // self loop (adj + eye)
            atomicOr(&mask[e * MWORDS + (e >> 5)], 1u << (e & 31));
        }
        return;
    }

    int bi = b >> 3, bj = b & 7;
    int w  = t >> 6, l = t & 63;
    int lr = l & 15, lk = l >> 4;

    // ---- stage wt rows [bj*64 .. +63] x 256k (32 KB) into LDS, coalesced ----
    #pragma unroll
    for (int it = 0; it < 8; ++it) {
        int flat = it * 256 + t;         // 2048 chunks of 8 bf16
        int row = flat >> 5;             // 0..63
        int c8  = flat & 31;             // k-chunk of 8
        uint4 v = *reinterpret_cast<const uint4*>(wt + (size_t)(bj * 64 + row) * INF_ + c8 * 8);
        *reinterpret_cast<uint4*>(&wls[row][c8 * 8]) = v;
    }
    __syncthreads();

    const ushort_t* ap = xb + (size_t)(bi * 64 + w * 16 + lr) * INF_ + lk * 8;

    f32x4 acc[4];
    #pragma unroll
    for (int c = 0; c < 4; ++c) acc[c] = (f32x4){0.f, 0.f, 0.f, 0.f};

    #pragma unroll
    for (int k0 = 0; k0 < INF_; k0 += 32) {
        U16x8 af;
        af.u = *reinterpret_cast<const uint4*>(ap + k0);
        #pragma unroll
        for (int c = 0; c < 4; ++c) {
            U16x8 bf_;
            bf_.u = *reinterpret_cast<const uint4*>(&wls[c * 16 + lr][k0 + lk * 8]);
            acc[c] = __builtin_amdgcn_mfma_f32_16x16x32_bf16(af.v, bf_.v, acc[c], 0, 0, 0);
        }
    }

    // C/D: col=lane&15, row=(lane>>4)*4+reg
    int growbase = bi * 64 + w * 16 + lk * 4;
    #pragma unroll
    for (int c = 0; c < 4; ++c) {
        int gcol = bj * 64 + c * 16 + lr;
        #pragma unroll
        for (int r = 0; r < 4; ++r)
            hout[(size_t)(growbase + r) * HO + gcol] = f32_to_bf16(acc[c][r]);
    }

    float ps[4] = {0.f, 0.f, 0.f, 0.f}, pd[4] = {0.f, 0.f, 0.f, 0.f};
    #pragma unroll
    for (int c = 0; c < 4; ++c) {
        int col64 = c * 16 + lr;
        float as_ = a[bj * 2 * FDIM + col64];
        float ad_ = a[bj * 2 * FDIM + FDIM + col64];
        #pragma unroll
        for (int r = 0; r < 4; ++r) {
            ps[r] += acc[c][r] * as_;
            pd[r] += acc[c][r] * ad_;
        }
    }
    #pragma unroll
    for (int r = 0; r < 4; ++r) {
        #pragma unroll
        for (int off = 1; off < 16; off <<= 1) {
            ps[r] += __shfl_xor(ps[r], off, 16);
            pd[r] += __shfl_xor(pd[r], off, 16);
        }
        if (lr == 0) {
            int grow = growbase + r;
            es[grow * HEADS + bj] = ps[r];
            ed[grow * HEADS + bj] = pd[r];
        }
    }
}

// ============ aggregation: ONE WAVE per row, 8 neighbors in flight ============
__device__ __forceinline__ void agg_one(float wgt, uint4 v, float* acc) {
    acc[0] += wgt * bf16_to_f32((ushort_t)(v.x & 0xFFFF));
    acc[1] += wgt * bf16_to_f32((ushort_t)(v.x >> 16));
    acc[2] += wgt * bf16_to_f32((ushort_t)(v.y & 0xFFFF));
    acc[3] += wgt * bf16_to_f32((ushort_t)(v.y >> 16));
    acc[4] += wgt * bf16_to_f32((ushort_t)(v.z & 0xFFFF));
    acc[5] += wgt * bf16_to_f32((ushort_t)(v.z >> 16));
    acc[6] += wgt * bf16_to_f32((ushort_t)(v.w & 0xFFFF));
    acc[7] += wgt * bf16_to_f32((ushort_t)(v.w >> 16));
}

__global__ __launch_bounds__(256) void gat_aggregate(const ushort_t* __restrict__ h,
                                                     const float* __restrict__ es,
                                                     const float* __restrict__ ed,
                                                     const unsigned int* __restrict__ mask,
                                                     float* __restrict__ out) {
    int w = threadIdx.x >> 6, lane = threadIdx.x & 63;
    int i = blockIdx.x * 4 + w;
    __shared__ unsigned short list_s[4][LCAP];
    unsigned short* mylist = list_s[w];

    const unsigned int* row = mask + (size_t)i * MWORDS;
    unsigned int b0 = row[lane], b1 = row[64 + lane];
    int c0 = __popc(b0), c1 = __popc(b1);
    int s0 = c0;
    #pragma unroll
    for (int off = 1; off < 64; off <<= 1) { int v = __shfl_up(s0, off); if (lane >= off) s0 += v; }
    int tot0 = __shfl(s0, 63);
    int s1 = c1;
    #pragma unroll
    for (int off = 1; off < 64; off <<= 1) { int v = __shfl_up(s1, off); if (lane >= off) s1 += v; }
    int deg = tot0 + __shfl(s1, 63);
    int p0 = s0 - c0;
    int p1 = tot0 + s1 - c1;
    int base0 = lane * 32, base1 = (64 + lane) * 32;
    while (b0) {
        int bit = __ffs(b0) - 1; b0 &= b0 - 1;
        if (p0 < LCAP) mylist[p0] = (unsigned short)(base0 + bit);
        ++p0;
    }
    while (b1) {
        int bit = __ffs(b1) - 1; b1 &= b1 - 1;
        if (p1 < LCAP) mylist[p1] = (unsigned short)(base1 + bit);
        ++p1;
    }
    __syncthreads();

    int hh = lane >> 3;
    int f0 = lane * 8;
    float es_h = es[i * HEADS + hh];
    float acc[8] = {0.f, 0.f, 0.f, 0.f, 0.f, 0.f, 0.f, 0.f};
    float den = 0.f;
    int jj = 0;
    // ---- 8 neighbors in flight ----
    for (; jj + 8 <= deg; jj += 8) {
        int jn[8];
        #pragma unroll
        for (int q = 0; q < 8; ++q) jn[q] = mylist[jj + q];
        float ev[8];
        #pragma unroll
        for (int q = 0; q < 8; ++q) ev[q] = ed[jn[q] * HEADS + hh];
        uint4 hv[8];
        #pragma unroll
        for (int q = 0; q < 8; ++q)
            hv[q] = *reinterpret_cast<const uint4*>(h + (size_t)jn[q] * HO + f0);
        #pragma unroll
        for (int q = 0; q < 8; ++q) {
            float s = es_h + ev[q];
            s = s > 0.f ? s : NEG_SLOPE * s;
            float wq = __expf(s);
            den += wq;
            agg_one(wq, hv[q], acc);
        }
    }
    for (; jj + 4 <= deg; jj += 4) {
        int jn[4];
        #pragma unroll
        for (int q = 0; q < 4; ++q) jn[q] = mylist[jj + q];
        float ev[4];
        #pragma unroll
        for (int q = 0; q < 4; ++q) ev[q] = ed[jn[q] * HEADS + hh];
        uint4 hv[4];
        #pragma unroll
        for (int q = 0; q < 4; ++q)
            hv[q] = *reinterpret_cast<const uint4*>(h + (size_t)jn[q] * HO + f0);
        #pragma unroll
        for (int q = 0; q < 4; ++q) {
            float s = es_h + ev[q];
            s = s > 0.f ? s : NEG_SLOPE * s;
            float wq = __expf(s);
            den += wq;
            agg_one(wq, hv[q], acc);
        }
    }
    for (; jj < deg; ++jj) {
        int ja = mylist[jj];
        float ea = ed[ja * HEADS + hh];
        uint4 va = *reinterpret_cast<const uint4*>(h + (size_t)ja * HO + f0);
        float sa = es_h + ea; sa = sa > 0.f ? sa : NEG_SLOPE * sa;
        float wa = __expf(sa);
        den += wa;
        agg_one(wa, va, acc);
    }

    float inv = 1.0f / den;
    f32x4 o0 = {acc[0] * inv, acc[1] * inv, acc[2] * inv, acc[3] * inv};
    f32x4 o1 = {acc[4] * inv, acc[5] * inv, acc[6] * inv, acc[7] * inv};
    float* op = out + (size_t)i * HO + f0;
    __builtin_nontemporal_store(o0, reinterpret_cast<f32x4*>(op));
    __builtin_nontemporal_store(o1, reinterpret_cast<f32x4*>(op + 4));
}

extern "C" void kernel_launch(void* const* d_in, const int* in_sizes, int n_in,
                              void* d_out, int out_size, void* d_ws, size_t ws_size,
                              hipStream_t stream) {
    const float* x  = (const float*)d_in[0];
    const int*   ei = (const int*)d_in[1];
    const float* W  = (const float*)d_in[2];
    const float* a  = (const float*)d_in[3];
    float* out = (float*)d_out;

    char* ws = (char*)d_ws;
    ushort_t* h  = (ushort_t*)ws;                               // 4 MB
    float* es = (float*)(ws + (size_t)NNODES * HO * 2);         // 128 KB
    float* ed = es + NNODES * HEADS;                            // 128 KB
    unsigned int* mask = (unsigned int*)(ed + NNODES * HEADS);  // 2 MB
    ushort_t* xb = (ushort_t*)(mask + (size_t)NNODES * MWORDS); // 2 MB
    ushort_t* wt = xb + (size_t)NNODES * INF_;                  // 256 KB

    hipLaunchKernelGGL(prep_kernel, dim3(ZB + XB + WTB), dim3(256), 0, stream,
                       x, W, mask, xb, wt);
    hipLaunchKernelGGL(gemm_adj, dim3(GEMM_BLOCKS + ADJ_BLOCKS), dim3(256), 0, stream,
                       xb, wt, a, ei, mask, h, es, ed);
    hipLaunchKernelGGL(gat_aggregate, dim3(NNODES / 4), dim3(256), 0, stream, h, es, ed, mask, out);
}

// Round 16
// 34.488 us; speedup vs baseline: 1.0296x; 1.0163x over previous
//
#include <hip/hip_runtime.h>

#define NNODES 4096
#define INF_   256
#define HEADS  8
#define FDIM   64
#define HO     512            // HEADS*FDIM
#define NEDGES 131072
#define NEG_SLOPE 0.2f
#define MWORDS 128            // 4096 bits / 32 per row

#define ZB 512                // prep: zero-mask blocks
#define XB 1024               // prep: x-convert blocks
#define WTB 32                // prep: W-transpose tiles
#define GEMM_BLOCKS 512       // 64 row-tiles x 8 col-tiles(heads)
#define ADJ_BLOCKS  512       // 131072 / 256
#define LCAP 1092             // per-row neighbor list capacity (max deg here ~70)

typedef unsigned short ushort_t;
typedef short bf16x8 __attribute__((ext_vector_type(8)));
typedef float f32x4  __attribute__((ext_vector_type(4)));

union U16x8 { uint4 u; bf16x8 v; };

__device__ __forceinline__ float bf16_to_f32(ushort_t u) {
    union { unsigned int i; float f; } c;
    c.i = ((unsigned int)u) << 16;
    return c.f;
}
__device__ __forceinline__ ushort_t f32_to_bf16(float f) {
    union { float f; unsigned int i; } c;
    c.f = f;
    unsigned int r = c.i + 0x7FFF + ((c.i >> 16) & 1);  // RNE
    return (ushort_t)(r >> 16);
}

// ============ prep: zero mask || x -> bf16 row-major || W -> W^T bf16 (LDS-tiled) ============
__global__ __launch_bounds__(256) void prep_kernel(const float* __restrict__ x,
                                                   const float* __restrict__ W,
                                                   unsigned int* __restrict__ mask,
                                                   ushort_t* __restrict__ xb,
                                                   ushort_t* __restrict__ wt) {
    __shared__ float tile[64][65];
    int b = blockIdx.x, t = threadIdx.x;
    if (b < ZB) {
        *reinterpret_cast<uint4*>(mask + (size_t)(b * 256 + t) * 4) = make_uint4(0u, 0u, 0u, 0u);
    } else if (b < ZB + XB) {
        int i = (b - ZB) * 256 + t;
        float4 v = *reinterpret_cast<const float4*>(x + (size_t)i * 4);
        ushort4 o;
        o.x = f32_to_bf16(v.x); o.y = f32_to_bf16(v.y);
        o.z = f32_to_bf16(v.z); o.w = f32_to_bf16(v.w);
        *reinterpret_cast<ushort4*>(xb + (size_t)i * 4) = o;
    } else {
        // ---- W^T tile: W[k0..k0+63][n0..n0+63] -> wt[n][k], coalesced both sides ----
        int wb = b - ZB - XB;          // 0..31
        int k0 = (wb >> 3) * 64;       // 4 k-tiles
        int n0 = (wb & 7) * 64;        // 8 n-tiles
        int row = t >> 2;
        #pragma unroll
        for (int it = 0; it < 4; ++it) {
            int f4 = (t & 3) + it * 4;  // 0..15
            float4 v = *reinterpret_cast<const float4*>(&W[(size_t)(k0 + row) * HO + n0 + f4 * 4]);
            tile[row][f4 * 4 + 0] = v.x;
            tile[row][f4 * 4 + 1] = v.y;
            tile[row][f4 * 4 + 2] = v.z;
            tile[row][f4 * 4 + 3] = v.w;
        }
        __syncthreads();
        int n = t >> 2;
        #pragma unroll
        for (int it = 0; it < 4; ++it) {
            int ch = (t & 3) + it * 4;  // k-chunk of 4
            ushort4 o;
            o.x = f32_to_bf16(tile[ch * 4 + 0][n]);
            o.y = f32_to_bf16(tile[ch * 4 + 1][n]);
            o.z = f32_to_bf16(tile[ch * 4 + 2][n]);
            o.w = f32_to_bf16(tile[ch * 4 + 3][n]);
            *reinterpret_cast<ushort4*>(&wt[(size_t)(n0 + n) * INF_ + k0 + ch * 4]) = o;
        }
    }
}

// ============ MFMA GEMM h = x@W, B-tile LDS-staged (+ es/ed epilogue) || adjacency ============
__global__ __launch_bounds__(256) void gemm_adj(const ushort_t* __restrict__ xb,
                                                const ushort_t* __restrict__ wt,
                                                const float* __restrict__ a,
                                                const int* __restrict__ ei,
                                                unsigned int* __restrict__ mask,
                                                ushort_t* __restrict__ hout,
                                                float* __restrict__ es,
                                                float* __restrict__ ed) {
    __shared__ ushort_t wls[64][264];   // B-tile [n-within-head][k], +8 pad -> free 2-way on b128 reads
    int b = blockIdx.x, t = threadIdx.x;

    if (b >= GEMM_BLOCKS) {
        int e = (b - GEMM_BLOCKS) * 256 + t;
        if (e < NEDGES) {
            int src = ei[e];
            int dst = ei[NEDGES + e];
            atomicOr(&mask[src * MWORDS + (dst >> 5)], 1u << (dst & 31));
        }
        if (e < NNODES) {  // self loop (adj + eye)
            atomicOr(&mask[e * MWORDS + (e >> 5)], 1u << (e & 31));
        }
        return;
    }

    int bi = b >> 3, bj = b & 7;
    int w  = t >> 6, l = t & 63;
    int lr = l & 15, lk = l >> 4;

    // ---- stage wt rows [bj*64 .. +63] x 256k (32 KB) into LDS, coalesced ----
    #pragma unroll
    for (int it = 0; it < 8; ++it) {
        int flat = it * 256 + t;         // 2048 chunks of 8 bf16
        int row = flat >> 5;             // 0..63
        int c8  = flat & 31;             // k-chunk of 8
        uint4 v = *reinterpret_cast<const uint4*>(wt + (size_t)(bj * 64 + row) * INF_ + c8 * 8);
        *reinterpret_cast<uint4*>(&wls[row][c8 * 8]) = v;
    }
    __syncthreads();

    const ushort_t* ap = xb + (size_t)(bi * 64 + w * 16 + lr) * INF_ + lk * 8;

    f32x4 acc[4];
    #pragma unroll
    for (int c = 0; c < 4; ++c) acc[c] = (f32x4){0.f, 0.f, 0.f, 0.f};

    #pragma unroll
    for (int k0 = 0; k0 < INF_; k0 += 32) {
        U16x8 af;
        af.u = *reinterpret_cast<const uint4*>(ap + k0);
        #pragma unroll
        for (int c = 0; c < 4; ++c) {
            U16x8 bf_;
            bf_.u = *reinterpret_cast<const uint4*>(&wls[c * 16 + lr][k0 + lk * 8]);
            acc[c] = __builtin_amdgcn_mfma_f32_16x16x32_bf16(af.v, bf_.v, acc[c], 0, 0, 0);
        }
    }

    // C/D: col=lane&15, row=(lane>>4)*4+reg
    int growbase = bi * 64 + w * 16 + lk * 4;
    #pragma unroll
    for (int c = 0; c < 4; ++c) {
        int gcol = bj * 64 + c * 16 + lr;
        #pragma unroll
        for (int r = 0; r < 4; ++r)
            hout[(size_t)(growbase + r) * HO + gcol] = f32_to_bf16(acc[c][r]);
    }

    float ps[4] = {0.f, 0.f, 0.f, 0.f}, pd[4] = {0.f, 0.f, 0.f, 0.f};
    #pragma unroll
    for (int c = 0; c < 4; ++c) {
        int col64 = c * 16 + lr;
        float as_ = a[bj * 2 * FDIM + col64];
        float ad_ = a[bj * 2 * FDIM + FDIM + col64];
        #pragma unroll
        for (int r = 0; r < 4; ++r) {
            ps[r] += acc[c][r] * as_;
            pd[r] += acc[c][r] * ad_;
        }
    }
    #pragma unroll
    for (int r = 0; r < 4; ++r) {
        #pragma unroll
        for (int off = 1; off < 16; off <<= 1) {
            ps[r] += __shfl_xor(ps[r], off, 16);
            pd[r] += __shfl_xor(pd[r], off, 16);
        }
        if (lr == 0) {
            int grow = growbase + r;
            es[grow * HEADS + bj] = ps[r];
            ed[grow * HEADS + bj] = pd[r];
        }
    }
}

// ============ aggregation: ONE WAVE per destination row, 4 neighbors in flight ============
__device__ __forceinline__ void agg_one(float wgt, uint4 v, float* acc) {
    acc[0] += wgt * bf16_to_f32((ushort_t)(v.x & 0xFFFF));
    acc[1] += wgt * bf16_to_f32((ushort_t)(v.x >> 16));
    acc[2] += wgt * bf16_to_f32((ushort_t)(v.y & 0xFFFF));
    acc[3] += wgt * bf16_to_f32((ushort_t)(v.y >> 16));
    acc[4] += wgt * bf16_to_f32((ushort_t)(v.z & 0xFFFF));
    acc[5] += wgt * bf16_to_f32((ushort_t)(v.z >> 16));
    acc[6] += wgt * bf16_to_f32((ushort_t)(v.w & 0xFFFF));
    acc[7] += wgt * bf16_to_f32((ushort_t)(v.w >> 16));
}

__global__ __launch_bounds__(256) void gat_aggregate(const ushort_t* __restrict__ h,
                                                     const float* __restrict__ es,
                                                     const float* __restrict__ ed,
                                                     const unsigned int* __restrict__ mask,
                                                     float* __restrict__ out) {
    int w = threadIdx.x >> 6, lane = threadIdx.x & 63;
    int i = blockIdx.x * 4 + w;
    __shared__ unsigned short list_s[4][LCAP];
    unsigned short* mylist = list_s[w];

    const unsigned int* row = mask + (size_t)i * MWORDS;
    unsigned int b0 = row[lane], b1 = row[64 + lane];
    int c0 = __popc(b0), c1 = __popc(b1);
    int s0 = c0;
    #pragma unroll
    for (int off = 1; off < 64; off <<= 1) { int v = __shfl_up(s0, off); if (lane >= off) s0 += v; }
    int tot0 = __shfl(s0, 63);
    int s1 = c1;
    #pragma unroll
    for (int off = 1; off < 64; off <<= 1) { int v = __shfl_up(s1, off); if (lane >= off) s1 += v; }
    int deg = tot0 + __shfl(s1, 63);
    int p0 = s0 - c0;
    int p1 = tot0 + s1 - c1;
    int base0 = lane * 32, base1 = (64 + lane) * 32;
    while (b0) {
        int bit = __ffs(b0) - 1; b0 &= b0 - 1;
        if (p0 < LCAP) mylist[p0] = (unsigned short)(base0 + bit);
        ++p0;
    }
    while (b1) {
        int bit = __ffs(b1) - 1; b1 &= b1 - 1;
        if (p1 < LCAP) mylist[p1] = (unsigned short)(base1 + bit);
        ++p1;
    }
    __syncthreads();

    int hh = lane >> 3;
    int f0 = lane * 8;
    float es_h = es[i * HEADS + hh];
    float acc[8] = {0.f, 0.f, 0.f, 0.f, 0.f, 0.f, 0.f, 0.f};
    float den = 0.f;
    int jj = 0;
    for (; jj + 4 <= deg; jj += 4) {
        int ja = mylist[jj], jb = mylist[jj + 1], jc = mylist[jj + 2], jd = mylist[jj + 3];
        float ea = ed[ja * HEADS + hh];
        float eb = ed[jb * HEADS + hh];
        float ec = ed[jc * HEADS + hh];
        float ee = ed[jd * HEADS + hh];
        uint4 va = *reinterpret_cast<const uint4*>(h + (size_t)ja * HO + f0);
        uint4 vb = *reinterpret_cast<const uint4*>(h + (size_t)jb * HO + f0);
        uint4 vc = *reinterpret_cast<const uint4*>(h + (size_t)jc * HO + f0);
        uint4 vd = *reinterpret_cast<const uint4*>(h + (size_t)jd * HO + f0);
        float sa = es_h + ea; sa = sa > 0.f ? sa : NEG_SLOPE * sa;
        float sb = es_h + eb; sb = sb > 0.f ? sb : NEG_SLOPE * sb;
        float sc = es_h + ec; sc = sc > 0.f ? sc : NEG_SLOPE * sc;
        float sd = es_h + ee; sd = sd > 0.f ? sd : NEG_SLOPE * sd;
        float wa = __expf(sa), wb = __expf(sb), wc = __expf(sc), wd = __expf(sd);
        den += (wa + wb) + (wc + wd);
        agg_one(wa, va, acc);
        agg_one(wb, vb, acc);
        agg_one(wc, vc, acc);
        agg_one(wd, vd, acc);
    }
    for (; jj < deg; ++jj) {
        int ja = mylist[jj];
        float ea = ed[ja * HEADS + hh];
        uint4 va = *reinterpret_cast<const uint4*>(h + (size_t)ja * HO + f0);
        float sa = es_h + ea; sa = sa > 0.f ? sa : NEG_SLOPE * sa;
        float wa = __expf(sa);
        den += wa;
        agg_one(wa, va, acc);
    }

    float inv = 1.0f / den;
    f32x4 o0 = {acc[0] * inv, acc[1] * inv, acc[2] * inv, acc[3] * inv};
    f32x4 o1 = {acc[4] * inv, acc[5] * inv, acc[6] * inv, acc[7] * inv};
    float* op = out + (size_t)i * HO + f0;
    __builtin_nontemporal_store(o0, reinterpret_cast<f32x4*>(op));
    __builtin_nontemporal_store(o1, reinterpret_cast<f32x4*>(op + 4));
}

extern "C" void kernel_launch(void* const* d_in, const int* in_sizes, int n_in,
                              void* d_out, int out_size, void* d_ws, size_t ws_size,
                              hipStream_t stream) {
    const float* x  = (const float*)d_in[0];
    const int*   ei = (const int*)d_in[1];
    const float* W  = (const float*)d_in[2];
    const float* a  = (const float*)d_in[3];
    float* out = (float*)d_out;

    char* ws = (char*)d_ws;
    ushort_t* h  = (ushort_t*)ws;                               // 4 MB
    float* es = (float*)(ws + (size_t)NNODES * HO * 2);         // 128 KB
    float* ed = es + NNODES * HEADS;                            // 128 KB
    unsigned int* mask = (unsigned int*)(ed + NNODES * HEADS);  // 2 MB
    ushort_t* xb = (ushort_t*)(mask + (size_t)NNODES * MWORDS); // 2 MB
    ushort_t* wt = xb + (size_t)NNODES * INF_;                  // 256 KB

    hipLaunchKernelGGL(prep_kernel, dim3(ZB + XB + WTB), dim3(256), 0, stream,
                       x, W, mask, xb, wt);
    hipLaunchKernelGGL(gemm_adj, dim3(GEMM_BLOCKS + ADJ_BLOCKS), dim3(256), 0, stream,
                       xb, wt, a, ei, mask, h, es, ed);
    hipLaunchKernelGGL(gat_aggregate, dim3(NNODES / 4), dim3(256), 0, stream, h, es, ed, mask, out);
}